// Round 1
// baseline (1916.417 us; speedup 1.0000x reference)
//
#include <hip/hip_runtime.h>
#include <cstdint>

// Problem constants (fixed by the reference): N=65536, D=128, M=4096, K=64
#define DDIM 128
#define MLAT 4096
#define KSEL 64

// ---------------------------------------------------------------------------
// K0: transpose W_dec [128][4096] -> WdT [4096][128]  (2 MB, trivial)
__global__ __launch_bounds__(256) void k_transpose(const float* __restrict__ Wdec,
                                                   float* __restrict__ WdT) {
    int tid = blockIdx.x * 256 + threadIdx.x;   // 0 .. 4096*128-1 == j*128+d
    int d = tid & (DDIM - 1);
    int j = tid >> 7;
    WdT[tid] = Wdec[(size_t)d * MLAT + j];
}

// ---------------------------------------------------------------------------
// K1: z_pre = relu((x - b_dec) @ W_enc^T + b_enc), written dense to zout.
// 64x64 tile, K=128 staged in two 64-halves. Each dot is ONE sequential-k
// fused-FMA chain (ascending k) to mirror BLAS sgemm microkernel rounding --
// required so top-k selection matches the numpy reference bit-for-bit.
// LDS stride 68 floats: A-reads 4 distinct banks (free), B-reads 2-way (free).
#define DOT4(r, c, av, bv)                         \
    acc[r][c] = fmaf(av.x, bv.x, acc[r][c]);       \
    acc[r][c] = fmaf(av.y, bv.y, acc[r][c]);       \
    acc[r][c] = fmaf(av.z, bv.z, acc[r][c]);       \
    acc[r][c] = fmaf(av.w, bv.w, acc[r][c]);

__global__ __launch_bounds__(256) void k_encode(const float* __restrict__ x,
                                                const float* __restrict__ Wenc,
                                                const float* __restrict__ benc,
                                                const float* __restrict__ bdec,
                                                float* __restrict__ zout) {
    __shared__ float As[64][68];
    __shared__ float Bs[64][68];
    const int t  = threadIdx.x;
    const int cb = blockIdx.x & 63;   // col tile (M/64 = 64)
    const int rb = blockIdx.x >> 6;   // row tile
    const int i0 = rb << 6, j0 = cb << 6;
    const int ty = t >> 4;            // 0..15 -> rows {ty, ty+16, ty+32, ty+48}
    const int tx = t & 15;            // 0..15 -> cols {tx, tx+16, tx+32, tx+48}
    const int sk   = (t & 15) << 2;   // staging k-offset within half (0..60)
    const int srow = t >> 4;          // staging row base (0..15)

    float acc[4][4] = {};

    for (int h = 0; h < 2; ++h) {
        // ---- stage 64 rows x 64 k of A (minus b_dec) and B into LDS
        const float4 bd = *(const float4*)(bdec + h * 64 + sk);
#pragma unroll
        for (int p = 0; p < 4; ++p) {
            int r = srow + (p << 4);
            float4 a = *(const float4*)(x + (size_t)(i0 + r) * DDIM + h * 64 + sk);
            a.x -= bd.x; a.y -= bd.y; a.z -= bd.z; a.w -= bd.w;
            *(float4*)(&As[r][sk]) = a;
            float4 b = *(const float4*)(Wenc + (size_t)(j0 + r) * DDIM + h * 64 + sk);
            *(float4*)(&Bs[r][sk]) = b;
        }
        __syncthreads();
        // ---- compute: k ascending, single FMA chain per (i,j)
#pragma unroll
        for (int kk = 0; kk < 64; kk += 4) {
            float4 a0 = *(const float4*)(&As[ty +  0][kk]);
            float4 a1 = *(const float4*)(&As[ty + 16][kk]);
            float4 a2 = *(const float4*)(&As[ty + 32][kk]);
            float4 a3 = *(const float4*)(&As[ty + 48][kk]);
            float4 b0 = *(const float4*)(&Bs[tx +  0][kk]);
            float4 b1 = *(const float4*)(&Bs[tx + 16][kk]);
            float4 b2 = *(const float4*)(&Bs[tx + 32][kk]);
            float4 b3 = *(const float4*)(&Bs[tx + 48][kk]);
            DOT4(0,0,a0,b0); DOT4(0,1,a0,b1); DOT4(0,2,a0,b2); DOT4(0,3,a0,b3);
            DOT4(1,0,a1,b0); DOT4(1,1,a1,b1); DOT4(1,2,a1,b2); DOT4(1,3,a1,b3);
            DOT4(2,0,a2,b0); DOT4(2,1,a2,b1); DOT4(2,2,a2,b2); DOT4(2,3,a2,b3);
            DOT4(3,0,a3,b0); DOT4(3,1,a3,b1); DOT4(3,2,a3,b2); DOT4(3,3,a3,b3);
        }
        __syncthreads();
    }
    // ---- epilogue: + b_enc, relu, store (strided cols -> scalar stores, 64B coalesced)
#pragma unroll
    for (int r = 0; r < 4; ++r) {
        size_t rowbase = (size_t)(i0 + ty + (r << 4)) * MLAT + j0;
#pragma unroll
        for (int c = 0; c < 4; ++c) {
            int j = tx + (c << 4);
            float v = acc[r][c] + benc[j0 + j];
            zout[rowbase + j] = fmaxf(v, 0.0f);
        }
    }
}

// ---------------------------------------------------------------------------
// K2: per-row exact top-64 (uint-bit bisection; relu => all >= 0 so uint order
// == float order), ties broken by LOWEST index (jax top_k semantics), z
// finalized in place, then sparse decode x_hat = b_dec + sum v_s * WdT[idx_s].
__device__ __forceinline__ int wredSum(int v) {
#pragma unroll
    for (int d = 32; d >= 1; d >>= 1) v += __shfl_xor(v, d, 64);
    return v;
}
__device__ __forceinline__ int wredMin(int v) {
#pragma unroll
    for (int d = 32; d >= 1; d >>= 1) v = min(v, __shfl_xor(v, d, 64));
    return v;
}

__global__ __launch_bounds__(256) void k_topk_decode(float* __restrict__ zbuf,
                                                     float* __restrict__ xhat,
                                                     const float* __restrict__ WdT,
                                                     const float* __restrict__ bdec) {
    __shared__ float sval[4][KSEL];
    __shared__ int   sidx[4][KSEL];
    const int lane = threadIdx.x & 63;
    const int wid  = threadIdx.x >> 6;
    const size_t row = (size_t)blockIdx.x * 4 + wid;
    float* zr = zbuf + row * MLAT;
    const uint4* zu = (const uint4*)zr;

    // element index for lane l, quad q, comp c:  idx = q*256 + l*4 + c
    uint4 u[16];
#pragma unroll
    for (int q = 0; q < 16; ++q) u[q] = zu[(q << 6) + lane];

    // ---- bisection for tau = 64th largest uint (values finite, >= 0)
    unsigned lo = 0u, hi = 0x7F800000u;
    while (hi - lo > 1u) {
        unsigned mid = (lo + hi) >> 1;
        int c = 0;
#pragma unroll
        for (int q = 0; q < 16; ++q) {
            c += (u[q].x >= mid); c += (u[q].y >= mid);
            c += (u[q].z >= mid); c += (u[q].w >= mid);
        }
        c = wredSum(c);
        if (c >= KSEL) lo = mid; else hi = mid;
    }
    const unsigned tau = lo;

    // ---- masks: strictly-greater and equal
    unsigned long long selgt = 0ull, seleq = 0ull;
#pragma unroll
    for (int q = 0; q < 16; ++q) {
        selgt |= (unsigned long long)(u[q].x > tau) << (4*q+0);
        selgt |= (unsigned long long)(u[q].y > tau) << (4*q+1);
        selgt |= (unsigned long long)(u[q].z > tau) << (4*q+2);
        selgt |= (unsigned long long)(u[q].w > tau) << (4*q+3);
        seleq |= (unsigned long long)(u[q].x == tau) << (4*q+0);
        seleq |= (unsigned long long)(u[q].y == tau) << (4*q+1);
        seleq |= (unsigned long long)(u[q].z == tau) << (4*q+2);
        seleq |= (unsigned long long)(u[q].w == tau) << (4*q+3);
    }
    int packed = wredSum((__popcll(selgt) << 16) | __popcll(seleq));
    int cgt = packed >> 16, m = packed & 0xFFFF;
    int need = KSEL - cgt;   // >= 1, and m >= need by construction

    unsigned long long sel;
    if (m == need) {
        sel = selgt | seleq;             // common path (usually m == need == 1)
    } else {
        // rare true-bit-tie: pick the `need` smallest global indices among equals
        sel = selgt;
        unsigned long long eq = seleq;
        for (int it = 0; it < need; ++it) {
            int bp = __ffsll((long long)eq) - 1;   // lane-local min idx = first set bit
            int best = (bp >= 0) ? (((bp >> 2) << 8) + (lane << 2) + (bp & 3)) : 0x7FFFFFFF;
            int g = wredMin(best);
            if (best == g) { sel |= 1ull << bp; eq &= ~(1ull << bp); }
        }
    }

    // ---- deterministic compaction position (no atomics): exclusive prefix over lanes
    int scnt = __popcll(sel);
    int pre = scnt;
#pragma unroll
    for (int d = 1; d < 64; d <<= 1) {
        int y = __shfl_up(pre, d, 64);
        if (lane >= d) pre += y;
    }
    int pos = pre - scnt;

    // ---- finalize z in place (value if selected else 0) + compact (v, idx) to LDS
    uint4* zw = (uint4*)zr;
#pragma unroll
    for (int q = 0; q < 16; ++q) {
        uint4 o;
        bool s0 = (sel >> (4*q+0)) & 1ull;
        bool s1 = (sel >> (4*q+1)) & 1ull;
        bool s2 = (sel >> (4*q+2)) & 1ull;
        bool s3 = (sel >> (4*q+3)) & 1ull;
        o.x = s0 ? u[q].x : 0u;
        o.y = s1 ? u[q].y : 0u;
        o.z = s2 ? u[q].z : 0u;
        o.w = s3 ? u[q].w : 0u;
        int base = (q << 8) + (lane << 2);
        if (s0) { sval[wid][pos] = __uint_as_float(u[q].x); sidx[wid][pos] = base + 0; ++pos; }
        if (s1) { sval[wid][pos] = __uint_as_float(u[q].y); sidx[wid][pos] = base + 1; ++pos; }
        if (s2) { sval[wid][pos] = __uint_as_float(u[q].z); sidx[wid][pos] = base + 2; ++pos; }
        if (s3) { sval[wid][pos] = __uint_as_float(u[q].w); sidx[wid][pos] = base + 3; ++pos; }
        zw[(q << 6) + lane] = o;
    }
    __syncthreads();

    // ---- decode: each lane owns d = lane and d = lane+64 (coalesced WdT reads)
    float a0 = bdec[lane], a1 = bdec[64 + lane];
#pragma unroll 4
    for (int s = 0; s < KSEL; ++s) {
        float v = sval[wid][s];
        int   j = sidx[wid][s];
        const float* w = WdT + (size_t)j * DDIM;
        a0 = fmaf(v, w[lane], a0);
        a1 = fmaf(v, w[64 + lane], a1);
    }
    xhat[row * DDIM + lane]      = a0;
    xhat[row * DDIM + 64 + lane] = a1;
}

// ---------------------------------------------------------------------------
extern "C" void kernel_launch(void* const* d_in, const int* in_sizes, int n_in,
                              void* d_out, int out_size, void* d_ws, size_t ws_size,
                              hipStream_t stream) {
    const float* x    = (const float*)d_in[0];
    const float* Wenc = (const float*)d_in[1];
    const float* benc = (const float*)d_in[2];
    const float* Wdec = (const float*)d_in[3];
    const float* bdec = (const float*)d_in[4];

    const int N = in_sizes[0] / DDIM;             // 65536
    float* xhat = (float*)d_out;                  // [N][128]
    float* zbuf = (float*)d_out + (size_t)N * DDIM; // [N][4096] (z_pre, then z)
    float* WdT  = (float*)d_ws;                   // [4096][128] = 2 MB

    k_transpose<<<dim3((MLAT * DDIM) / 256), dim3(256), 0, stream>>>(Wdec, WdT);
    k_encode<<<dim3((N / 64) * (MLAT / 64)), dim3(256), 0, stream>>>(x, Wenc, benc, bdec, zbuf);
    k_topk_decode<<<dim3(N / 4), dim3(256), 0, stream>>>(zbuf, xhat, WdT, bdec);
}

// Round 2
// 1511.851 us; speedup vs baseline: 1.2676x; 1.2676x over previous
//
#include <hip/hip_runtime.h>
#include <cstdint>

// Problem constants (fixed by the reference): N=65536, D=128, M=4096, K=64
#define DDIM 128
#define MLAT 4096
#define KSEL 64

// ---------------------------------------------------------------------------
// K0: transpose W_dec [128][4096] -> WdT [4096][128]  (2 MB, trivial)
__global__ __launch_bounds__(256) void k_transpose(const float* __restrict__ Wdec,
                                                   float* __restrict__ WdT) {
    int tid = blockIdx.x * 256 + threadIdx.x;   // 0 .. 4096*128-1 == j*128+d
    int d = tid & (DDIM - 1);
    int j = tid >> 7;
    WdT[tid] = Wdec[(size_t)d * MLAT + j];
}

// ---------------------------------------------------------------------------
// K1 v2: z_pre = relu((x - b_dec) @ W_enc^T + b_enc), dense to zout.
// 128x128 block tile, 256 threads, 8x8 strided register tile, K in two
// 64-halves in LDS. 16 FMA per ds_read_b128 (was 8 in v1). Accumulation
// order per output is IDENTICAL to v1 (single fmaf chain, k ascending:
// half -> kk -> xyzw) -- required so top-k matches the np/BLAS reference.
__global__ __launch_bounds__(256, 2) void k_encode(const float* __restrict__ x,
                                                   const float* __restrict__ Wenc,
                                                   const float* __restrict__ benc,
                                                   const float* __restrict__ bdec,
                                                   float* __restrict__ zout) {
    __shared__ float As[128][68];
    __shared__ float Bs[128][68];
    const int t  = threadIdx.x;
    const int cb = blockIdx.x & 31;   // col tile (M/128 = 32)
    const int rb = blockIdx.x >> 5;   // row tile (N/128 = 512)
    const int i0 = rb << 7, j0 = cb << 7;
    const int ty = t >> 4;            // 0..15 -> rows {ty + 16m}
    const int tx = t & 15;            // 0..15 -> cols {tx + 16n}
    const int sk = tx << 2;           // staging k-offset within half (0..60)

    float acc[8][8] = {};

    for (int h = 0; h < 2; ++h) {
        // ---- stage 128 rows x 64 k of A (minus b_dec) and B into LDS
        const float4 bd = *(const float4*)(bdec + h * 64 + sk);
#pragma unroll
        for (int p = 0; p < 8; ++p) {
            int r = ty + (p << 4);
            float4 a = *(const float4*)(x + (size_t)(i0 + r) * DDIM + h * 64 + sk);
            a.x -= bd.x; a.y -= bd.y; a.z -= bd.z; a.w -= bd.w;
            *(float4*)(&As[r][sk]) = a;
            *(float4*)(&Bs[r][sk]) = *(const float4*)(Wenc + (size_t)(j0 + r) * DDIM + h * 64 + sk);
        }
        __syncthreads();
        // ---- compute: k ascending, single FMA chain per (i,j)
#pragma unroll 2
        for (int kk = 0; kk < 64; kk += 4) {
            float4 a[8], b[8];
#pragma unroll
            for (int m = 0; m < 8; ++m) a[m] = *(const float4*)(&As[ty + (m << 4)][kk]);
#pragma unroll
            for (int n = 0; n < 8; ++n) b[n] = *(const float4*)(&Bs[tx + (n << 4)][kk]);
#pragma unroll
            for (int m = 0; m < 8; ++m)
#pragma unroll
                for (int n = 0; n < 8; ++n) {
                    acc[m][n] = fmaf(a[m].x, b[n].x, acc[m][n]);
                    acc[m][n] = fmaf(a[m].y, b[n].y, acc[m][n]);
                    acc[m][n] = fmaf(a[m].z, b[n].z, acc[m][n]);
                    acc[m][n] = fmaf(a[m].w, b[n].w, acc[m][n]);
                }
        }
        __syncthreads();
    }
    // ---- epilogue: + b_enc, relu, store
    float bn[8];
#pragma unroll
    for (int n = 0; n < 8; ++n) bn[n] = benc[j0 + tx + (n << 4)];
#pragma unroll
    for (int m = 0; m < 8; ++m) {
        size_t rowbase = (size_t)(i0 + ty + (m << 4)) * MLAT + j0;
#pragma unroll
        for (int n = 0; n < 8; ++n)
            zout[rowbase + tx + (n << 4)] = fmaxf(acc[m][n] + bn[n], 0.0f);
    }
}

// ---------------------------------------------------------------------------
// K2: per-row exact top-64 (uint-bit bisection with count==64 early exit;
// relu => all >= 0 so uint order == float order), ties broken by LOWEST
// index (jax top_k semantics), z finalized in place, then sparse decode.
__device__ __forceinline__ int wredSum(int v) {
#pragma unroll
    for (int d = 32; d >= 1; d >>= 1) v += __shfl_xor(v, d, 64);
    return v;
}
__device__ __forceinline__ int wredMin(int v) {
#pragma unroll
    for (int d = 32; d >= 1; d >>= 1) v = min(v, __shfl_xor(v, d, 64));
    return v;
}

__global__ __launch_bounds__(256) void k_topk_decode(float* __restrict__ zbuf,
                                                     float* __restrict__ xhat,
                                                     const float* __restrict__ WdT,
                                                     const float* __restrict__ bdec) {
    __shared__ float sval[4][KSEL];
    __shared__ int   sidx[4][KSEL];
    const int lane = threadIdx.x & 63;
    const int wid  = threadIdx.x >> 6;
    const size_t row = (size_t)blockIdx.x * 4 + wid;
    float* zr = zbuf + row * MLAT;
    const uint4* zu = (const uint4*)zr;

    // element index for lane l, quad q, comp c:  idx = q*256 + l*4 + c
    uint4 u[16];
#pragma unroll
    for (int q = 0; q < 16; ++q) u[q] = zu[(q << 6) + lane];

    // ---- bisection for a separating threshold (early exit when count==64)
    unsigned lo = 0u, hi = 0x7F800000u;
    unsigned thr = 0u;
    bool exact = false;
    while (hi - lo > 1u) {
        unsigned mid = lo + ((hi - lo) >> 1);
        int c = 0;
#pragma unroll
        for (int q = 0; q < 16; ++q) {
            c += (u[q].x >= mid); c += (u[q].y >= mid);
            c += (u[q].z >= mid); c += (u[q].w >= mid);
        }
        c = wredSum(c);
        if (c == KSEL) { thr = mid; exact = true; break; }
        if (c > KSEL) lo = mid; else hi = mid;
    }

    unsigned long long sel;
    if (exact) {
        // clean separation: exactly 64 values >= thr
        sel = 0ull;
#pragma unroll
        for (int q = 0; q < 16; ++q) {
            sel |= (unsigned long long)(u[q].x >= thr) << (4*q+0);
            sel |= (unsigned long long)(u[q].y >= thr) << (4*q+1);
            sel |= (unsigned long long)(u[q].z >= thr) << (4*q+2);
            sel |= (unsigned long long)(u[q].w >= thr) << (4*q+3);
        }
    } else {
        // tau = lo is the 64th largest; handle ties by lowest global index
        const unsigned tau = lo;
        unsigned long long selgt = 0ull, seleq = 0ull;
#pragma unroll
        for (int q = 0; q < 16; ++q) {
            selgt |= (unsigned long long)(u[q].x > tau) << (4*q+0);
            selgt |= (unsigned long long)(u[q].y > tau) << (4*q+1);
            selgt |= (unsigned long long)(u[q].z > tau) << (4*q+2);
            selgt |= (unsigned long long)(u[q].w > tau) << (4*q+3);
            seleq |= (unsigned long long)(u[q].x == tau) << (4*q+0);
            seleq |= (unsigned long long)(u[q].y == tau) << (4*q+1);
            seleq |= (unsigned long long)(u[q].z == tau) << (4*q+2);
            seleq |= (unsigned long long)(u[q].w == tau) << (4*q+3);
        }
        int packed = wredSum((__popcll(selgt) << 16) | __popcll(seleq));
        int cgt = packed >> 16, m = packed & 0xFFFF;
        int need = KSEL - cgt;   // >= 1, and m >= need by construction
        if (m == need) {
            sel = selgt | seleq;
        } else {
            sel = selgt;
            unsigned long long eq = seleq;
            for (int it = 0; it < need; ++it) {
                int bp = __ffsll((long long)eq) - 1;
                int best = (bp >= 0) ? (((bp >> 2) << 8) + (lane << 2) + (bp & 3)) : 0x7FFFFFFF;
                int g = wredMin(best);
                if (best == g) { sel |= 1ull << bp; eq &= ~(1ull << bp); }
            }
        }
    }

    // ---- deterministic compaction position: exclusive prefix over lanes
    int scnt = __popcll(sel);
    int pre = scnt;
#pragma unroll
    for (int d = 1; d < 64; d <<= 1) {
        int y = __shfl_up(pre, d, 64);
        if (lane >= d) pre += y;
    }
    int pos = pre - scnt;

    // ---- finalize z in place + compact (v, idx) to LDS
    uint4* zw = (uint4*)zr;
#pragma unroll
    for (int q = 0; q < 16; ++q) {
        uint4 o;
        bool s0 = (sel >> (4*q+0)) & 1ull;
        bool s1 = (sel >> (4*q+1)) & 1ull;
        bool s2 = (sel >> (4*q+2)) & 1ull;
        bool s3 = (sel >> (4*q+3)) & 1ull;
        o.x = s0 ? u[q].x : 0u;
        o.y = s1 ? u[q].y : 0u;
        o.z = s2 ? u[q].z : 0u;
        o.w = s3 ? u[q].w : 0u;
        int base = (q << 8) + (lane << 2);
        if (s0) { sval[wid][pos] = __uint_as_float(u[q].x); sidx[wid][pos] = base + 0; ++pos; }
        if (s1) { sval[wid][pos] = __uint_as_float(u[q].y); sidx[wid][pos] = base + 1; ++pos; }
        if (s2) { sval[wid][pos] = __uint_as_float(u[q].z); sidx[wid][pos] = base + 2; ++pos; }
        if (s3) { sval[wid][pos] = __uint_as_float(u[q].w); sidx[wid][pos] = base + 3; ++pos; }
        zw[(q << 6) + lane] = o;
    }
    __syncthreads();

    // ---- decode: each lane owns d = lane and d = lane+64
    float a0 = bdec[lane], a1 = bdec[64 + lane];
#pragma unroll 4
    for (int s = 0; s < KSEL; ++s) {
        float v = sval[wid][s];
        int   j = sidx[wid][s];
        const float* w = WdT + (size_t)j * DDIM;
        a0 = fmaf(v, w[lane], a0);
        a1 = fmaf(v, w[64 + lane], a1);
    }
    xhat[row * DDIM + lane]      = a0;
    xhat[row * DDIM + 64 + lane] = a1;
}

// ---------------------------------------------------------------------------
extern "C" void kernel_launch(void* const* d_in, const int* in_sizes, int n_in,
                              void* d_out, int out_size, void* d_ws, size_t ws_size,
                              hipStream_t stream) {
    const float* x    = (const float*)d_in[0];
    const float* Wenc = (const float*)d_in[1];
    const float* benc = (const float*)d_in[2];
    const float* Wdec = (const float*)d_in[3];
    const float* bdec = (const float*)d_in[4];

    const int N = in_sizes[0] / DDIM;               // 65536
    float* xhat = (float*)d_out;                    // [N][128]
    float* zbuf = (float*)d_out + (size_t)N * DDIM; // [N][4096] (z_pre, then z)
    float* WdT  = (float*)d_ws;                     // [4096][128] = 2 MB

    k_transpose<<<dim3((MLAT * DDIM) / 256), dim3(256), 0, stream>>>(Wdec, WdT);
    k_encode<<<dim3((N / 128) * (MLAT / 128)), dim3(256), 0, stream>>>(x, Wenc, benc, bdec, zbuf);
    k_topk_decode<<<dim3(N / 4), dim3(256), 0, stream>>>(zbuf, xhat, WdT, bdec);
}

// Round 3
// 1184.346 us; speedup vs baseline: 1.6181x; 1.2765x over previous
//
#include <hip/hip_runtime.h>
#include <cstdint>

#define DDIM 128
#define MLAT 4096
#define KSEL 64

typedef __bf16 bf16x8 __attribute__((ext_vector_type(8)));
typedef float  f32x4  __attribute__((ext_vector_type(4)));

// ---------------------------------------------------------------------------
// K0a: split (x - b_dec) into bf16 hi/lo pair arrays (RN-even), 4 elems/thread
__global__ __launch_bounds__(256) void k_split_x(const float* __restrict__ x,
                                                 const float* __restrict__ bdec,
                                                 ushort* __restrict__ xhi,
                                                 ushort* __restrict__ xlo) {
    int e = (blockIdx.x * 256 + threadIdx.x) * 4;
    float4 v = *(const float4*)(x + e);
    float4 bd = *(const float4*)(bdec + (e & 127));
    float a[4] = {v.x - bd.x, v.y - bd.y, v.z - bd.z, v.w - bd.w};
    ushort4 h, l;
    ushort* hp = (ushort*)&h; ushort* lp = (ushort*)&l;
#pragma unroll
    for (int i = 0; i < 4; ++i) {
        unsigned ua = __float_as_uint(a[i]);
        unsigned rh = (ua + 0x7FFFu + ((ua >> 16) & 1u)) & 0xFFFF0000u;
        float lo = a[i] - __uint_as_float(rh);
        unsigned ul = __float_as_uint(lo);
        unsigned rl = ul + 0x7FFFu + ((ul >> 16) & 1u);
        hp[i] = (ushort)(rh >> 16);
        lp[i] = (ushort)(rl >> 16);
    }
    *(ushort4*)(xhi + e) = h;
    *(ushort4*)(xlo + e) = l;
}

// K0b: split W_enc into bf16 hi/lo
__global__ __launch_bounds__(256) void k_split_w(const float* __restrict__ w,
                                                 ushort* __restrict__ whi,
                                                 ushort* __restrict__ wlo) {
    int e = (blockIdx.x * 256 + threadIdx.x) * 4;
    float4 v = *(const float4*)(w + e);
    float a[4] = {v.x, v.y, v.z, v.w};
    ushort4 h, l;
    ushort* hp = (ushort*)&h; ushort* lp = (ushort*)&l;
#pragma unroll
    for (int i = 0; i < 4; ++i) {
        unsigned ua = __float_as_uint(a[i]);
        unsigned rh = (ua + 0x7FFFu + ((ua >> 16) & 1u)) & 0xFFFF0000u;
        float lo = a[i] - __uint_as_float(rh);
        unsigned ul = __float_as_uint(lo);
        unsigned rl = ul + 0x7FFFu + ((ul >> 16) & 1u);
        hp[i] = (ushort)(rh >> 16);
        lp[i] = (ushort)(rl >> 16);
    }
    *(ushort4*)(whi + e) = h;
    *(ushort4*)(wlo + e) = l;
}

// K0c: transpose W_dec [128][4096] -> WdT [4096][128]
__global__ __launch_bounds__(256) void k_transpose(const float* __restrict__ Wdec,
                                                   float* __restrict__ WdT) {
    int tid = blockIdx.x * 256 + threadIdx.x;
    int d = tid & (DDIM - 1);
    int j = tid >> 7;
    WdT[tid] = Wdec[(size_t)d * MLAT + j];
}

// ---------------------------------------------------------------------------
// K1 v3: z~ = relu((x-b_dec) @ W_enc^T + b_enc) via split-bf16 MFMA.
// 512 blocks (2/CU), each owns 128 rows x full M (16 col-passes of 256).
// A splits staged once in LDS (XOR-swizzled); B frags streamed from L2.
// mfma_f32_16x16x32_bf16: A lane l holds A[l&15][(l>>4)*8 + j];
//                         B lane l holds B[(l>>4)*8 + j][l&15];
//                         C/D: col=lane&15, row=(lane>>4)*4+reg.
__global__ __launch_bounds__(256, 2) void k_encode_mfma(
        const ushort* __restrict__ xhi, const ushort* __restrict__ xlo,
        const ushort* __restrict__ whi, const ushort* __restrict__ wlo,
        const float* __restrict__ benc, float* __restrict__ zout) {
    __shared__ __attribute__((aligned(16))) ushort Ah[128 * 128];
    __shared__ __attribute__((aligned(16))) ushort Al[128 * 128];

    const int t    = threadIdx.x;
    const int lane = t & 63;
    const int w    = t >> 6;
    const int i0   = blockIdx.x << 7;

    // ---- stage A splits, swizzled: byte = row*256 + k*2, ^ ((row&7)<<4)
    {
        int row = t >> 1, half = t & 1;
        const ushort* sh = xhi + (size_t)(i0 + row) * DDIM + half * 64;
        const ushort* sl = xlo + (size_t)(i0 + row) * DDIM + half * 64;
        int base = row * 256 + half * 128;
        int swz  = (row & 7) << 4;
#pragma unroll
        for (int j = 0; j < 8; ++j) {
            int off = (base + j * 16) ^ swz;
            *(bf16x8*)((char*)Ah + off) = *(const bf16x8*)(sh + j * 8);
            *(bf16x8*)((char*)Al + off) = *(const bf16x8*)(sl + j * 8);
        }
    }
    __syncthreads();

    const int lr = lane & 15;
    const int lq = lane >> 4;

    for (int cp = 0; cp < 16; ++cp) {
        const int jb = cp * 256 + (w << 6);
        f32x4 acc[8][4];
#pragma unroll
        for (int rf = 0; rf < 8; ++rf)
#pragma unroll
            for (int cf = 0; cf < 4; ++cf) acc[rf][cf] = (f32x4){0.f, 0.f, 0.f, 0.f};

        for (int ks = 0; ks < 4; ++ks) {
            bf16x8 bh[4], bl[4];
#pragma unroll
            for (int cf = 0; cf < 4; ++cf) {
                size_t boff = (size_t)(jb + cf * 16 + lr) * DDIM + ks * 32 + lq * 8;
                bh[cf] = *(const bf16x8*)(whi + boff);
                bl[cf] = *(const bf16x8*)(wlo + boff);
            }
#pragma unroll
            for (int rf = 0; rf < 8; ++rf) {
                int row = rf * 16 + lr;
                int off = (row * 256 + ks * 64 + lq * 16) ^ ((row & 7) << 4);
                bf16x8 ah = *(const bf16x8*)((const char*)Ah + off);
                bf16x8 al = *(const bf16x8*)((const char*)Al + off);
#pragma unroll
                for (int cf = 0; cf < 4; ++cf) {
                    acc[rf][cf] = __builtin_amdgcn_mfma_f32_16x16x32_bf16(ah, bh[cf], acc[rf][cf], 0, 0, 0);
                    acc[rf][cf] = __builtin_amdgcn_mfma_f32_16x16x32_bf16(ah, bl[cf], acc[rf][cf], 0, 0, 0);
                    acc[rf][cf] = __builtin_amdgcn_mfma_f32_16x16x32_bf16(al, bh[cf], acc[rf][cf], 0, 0, 0);
                }
            }
        }
        // ---- epilogue: + b_enc, relu, store f32
#pragma unroll
        for (int rf = 0; rf < 8; ++rf)
#pragma unroll
            for (int cf = 0; cf < 4; ++cf) {
                int col = jb + cf * 16 + lr;
                float be = benc[col];
#pragma unroll
                for (int r = 0; r < 4; ++r) {
                    int row = i0 + rf * 16 + lq * 4 + r;
                    zout[(size_t)row * MLAT + col] = fmaxf(acc[rf][cf][r] + be, 0.f);
                }
            }
    }
}

// ---------------------------------------------------------------------------
// K2: per-row top-64 on z~ with exact-band fixup, z finalized, sparse decode.
__device__ __forceinline__ int wredSum(int v) {
#pragma unroll
    for (int d = 32; d >= 1; d >>= 1) v += __shfl_xor(v, d, 64);
    return v;
}

__global__ __launch_bounds__(256) void k_topk_decode(
        float* __restrict__ zbuf, float* __restrict__ xhat,
        const float* __restrict__ WdT, const float* __restrict__ bdec,
        const float* __restrict__ x, const float* __restrict__ Wenc,
        const float* __restrict__ benc) {
    __shared__ float sval[4][KSEL];
    __shared__ int   sidx[4][KSEL];
    __shared__ float bval[4][128];
    __shared__ int   bidx[4][128];
    __shared__ unsigned char bselm[4][128];

    const int lane = threadIdx.x & 63;
    const int wid  = threadIdx.x >> 6;
    const size_t row = (size_t)blockIdx.x * 4 + wid;
    float* zr = zbuf + row * MLAT;
    const uint4* zu = (const uint4*)zr;

    // element index: q*256 + lane*4 + c
    uint4 u[16];
#pragma unroll
    for (int q = 0; q < 16; ++q) u[q] = zu[(q << 6) + lane];

    // ---- bisection for threshold T (early exit when count == 64)
    unsigned lo = 0u, hi = 0x7F800000u, T = 0u;
    bool exact = false;
    while (hi - lo > 1u) {
        unsigned mid = lo + ((hi - lo) >> 1);
        int c = 0;
#pragma unroll
        for (int q = 0; q < 16; ++q) {
            c += (u[q].x >= mid); c += (u[q].y >= mid);
            c += (u[q].z >= mid); c += (u[q].w >= mid);
        }
        c = wredSum(c);
        if (c == KSEL) { T = mid; exact = true; break; }
        if (c > KSEL) lo = mid; else hi = mid;
    }
    if (!exact) T = lo;   // T == bits of 64th-largest value

    // ---- classification bands (float margins; values >= 0 so uint order ok)
    const float tau   = __uint_as_float(T);
    const float DELTA = 2.5e-4f;   // >> 2*eps(approx) ~ 4e-5
    const float PAD   = 5.0e-5f;   // 2*eps guard on the IN edge
    const unsigned DH = __float_as_uint(tau + DELTA + PAD);
    const unsigned DL = __float_as_uint(fmaxf(tau - DELTA, 0.f));

    unsigned long long inm = 0ull, bandm = 0ull;
#pragma unroll
    for (int q = 0; q < 16; ++q) {
        unsigned vv[4] = {u[q].x, u[q].y, u[q].z, u[q].w};
#pragma unroll
        for (int c = 0; c < 4; ++c) {
            unsigned long long bit = 1ull << (4 * q + c);
            if (vv[c] > DH) inm |= bit;
            else if (vv[c] >= DL) bandm |= bit;
        }
    }
    int packed = wredSum((__popcll(inm) << 16) | __popcll(bandm));
    int A = packed >> 16, BCt = packed & 0xFFFF;
    int need = KSEL - A;

    unsigned long long sel;
    if (need <= 0) {
        sel = inm;
    } else if (BCt == need) {
        sel = inm | bandm;
    } else {
        // ---- exact fixup: recompute band members with np-order f32 chain
        int BC2 = min(BCt, 128);
        int bc = __popcll(bandm);
        int pre = bc;
#pragma unroll
        for (int d = 1; d < 64; d <<= 1) {
            int y = __shfl_up(pre, d, 64);
            if (lane >= d) pre += y;
        }
        int sbase = pre - bc;
        {
            unsigned long long mm = bandm; int o = 0;
            while (mm) {
                int bp = __ffsll((long long)mm) - 1; mm &= mm - 1;
                int slot = sbase + o; ++o;
                if (slot < 128) bidx[wid][slot] = ((bp >> 2) << 8) + (lane << 2) + (bp & 3);
            }
        }
        for (int s = lane; s < BC2; s += 64) {
            int j = bidx[wid][s];
            const float* wr = Wenc + (size_t)j * DDIM;
            const float* xr = x + row * DDIM;
            float a = 0.f;
            for (int k = 0; k < DDIM; ++k) a = fmaf(xr[k] - bdec[k], wr[k], a);
            bval[wid][s] = fmaxf(a + benc[j], 0.f);
        }
        if (lane == 0) {
            for (int s = 0; s < BC2; ++s) bselm[wid][s] = 0;
            int take = min(need, BC2);
            for (int it = 0; it < take; ++it) {
                float bv = -1.f; int bi = 0x7FFFFFFF, bs = -1;
                for (int s = 0; s < BC2; ++s) {
                    if (bselm[wid][s]) continue;
                    float v = bval[wid][s]; int j = bidx[wid][s];
                    if (v > bv || (v == bv && j < bi)) { bv = v; bi = j; bs = s; }
                }
                bselm[wid][bs] = 1;
            }
        }
        sel = inm;
        {
            unsigned long long mm = bandm; int o = 0;
            while (mm) {
                int bp = __ffsll((long long)mm) - 1; mm &= mm - 1;
                int slot = sbase + o; ++o;
                if (slot < 128 && bselm[wid][slot]) sel |= 1ull << bp;
            }
        }
    }

    // ---- compaction position: exclusive prefix over lanes
    int scnt = __popcll(sel);
    int pre = scnt;
#pragma unroll
    for (int d = 1; d < 64; d <<= 1) {
        int y = __shfl_up(pre, d, 64);
        if (lane >= d) pre += y;
    }
    int pos = pre - scnt;
    int total = __shfl(pre, 63, 64);

    // ---- finalize z in place + compact (v, idx) to LDS
    uint4* zw = (uint4*)zr;
#pragma unroll
    for (int q = 0; q < 16; ++q) {
        uint4 o;
        bool s0 = (sel >> (4 * q + 0)) & 1ull;
        bool s1 = (sel >> (4 * q + 1)) & 1ull;
        bool s2 = (sel >> (4 * q + 2)) & 1ull;
        bool s3 = (sel >> (4 * q + 3)) & 1ull;
        o.x = s0 ? u[q].x : 0u;
        o.y = s1 ? u[q].y : 0u;
        o.z = s2 ? u[q].z : 0u;
        o.w = s3 ? u[q].w : 0u;
        int base = (q << 8) + (lane << 2);
        if (s0) { sval[wid][pos] = __uint_as_float(u[q].x); sidx[wid][pos] = base + 0; ++pos; }
        if (s1) { sval[wid][pos] = __uint_as_float(u[q].y); sidx[wid][pos] = base + 1; ++pos; }
        if (s2) { sval[wid][pos] = __uint_as_float(u[q].z); sidx[wid][pos] = base + 2; ++pos; }
        if (s3) { sval[wid][pos] = __uint_as_float(u[q].w); sidx[wid][pos] = base + 3; ++pos; }
        zw[(q << 6) + lane] = o;
    }
    __syncthreads();

    // ---- decode
    float a0 = bdec[lane], a1 = bdec[64 + lane];
    int tt = min(total, KSEL);
#pragma unroll 4
    for (int s = 0; s < tt; ++s) {
        float v = sval[wid][s];
        int   j = sidx[wid][s];
        const float* wv = WdT + (size_t)j * DDIM;
        a0 = fmaf(v, wv[lane], a0);
        a1 = fmaf(v, wv[64 + lane], a1);
    }
    xhat[row * DDIM + lane]      = a0;
    xhat[row * DDIM + 64 + lane] = a1;
}

// ---------------------------------------------------------------------------
extern "C" void kernel_launch(void* const* d_in, const int* in_sizes, int n_in,
                              void* d_out, int out_size, void* d_ws, size_t ws_size,
                              hipStream_t stream) {
    const float* x    = (const float*)d_in[0];
    const float* Wenc = (const float*)d_in[1];
    const float* benc = (const float*)d_in[2];
    const float* Wdec = (const float*)d_in[3];
    const float* bdec = (const float*)d_in[4];

    const int N = in_sizes[0] / DDIM;               // 65536
    float* xhat = (float*)d_out;                    // [N][128] f32 (final)
    float* zbuf = (float*)d_out + (size_t)N * DDIM; // [N][4096]

    // x splits live in the xhat region until decode (exact fit: N*128*4 bytes)
    ushort* xhi = (ushort*)d_out;
    ushort* xlo = xhi + (size_t)N * DDIM;

    // workspace: whi | wlo | WdT  (1 MB + 1 MB + 2 MB)
    ushort* whi = (ushort*)d_ws;
    ushort* wlo = whi + (size_t)MLAT * DDIM;
    float*  WdT = (float*)((char*)d_ws + 2u * 1024u * 1024u);

    k_split_x<<<dim3((N * DDIM) / 1024), dim3(256), 0, stream>>>(x, bdec, xhi, xlo);
    k_split_w<<<dim3((MLAT * DDIM) / 1024), dim3(256), 0, stream>>>(Wenc, whi, wlo);
    k_transpose<<<dim3((MLAT * DDIM) / 256), dim3(256), 0, stream>>>(Wdec, WdT);
    k_encode_mfma<<<dim3(N / 128), dim3(256), 0, stream>>>(xhi, xlo, whi, wlo, benc, zbuf);
    k_topk_decode<<<dim3(N / 4), dim3(256), 0, stream>>>(zbuf, xhat, WdT, bdec, x, Wenc, benc);
}

// Round 5
// 1118.250 us; speedup vs baseline: 1.7138x; 1.0591x over previous
//
#include <hip/hip_runtime.h>
#include <cstdint>

#define DDIM 128
#define MLAT 4096
#define KSEL 64

typedef __bf16 bf16x8 __attribute__((ext_vector_type(8)));
typedef float  f32x4  __attribute__((ext_vector_type(4)));

// ---------------------------------------------------------------------------
// K0a: split (x - b_dec) into bf16 hi/lo pair arrays (RN-even), 4 elems/thread
__global__ __launch_bounds__(256) void k_split_x(const float* __restrict__ x,
                                                 const float* __restrict__ bdec,
                                                 ushort* __restrict__ xhi,
                                                 ushort* __restrict__ xlo) {
    int e = (blockIdx.x * 256 + threadIdx.x) * 4;
    float4 v = *(const float4*)(x + e);
    float4 bd = *(const float4*)(bdec + (e & 127));
    float a[4] = {v.x - bd.x, v.y - bd.y, v.z - bd.z, v.w - bd.w};
    ushort4 h, l;
    ushort* hp = (ushort*)&h; ushort* lp = (ushort*)&l;
#pragma unroll
    for (int i = 0; i < 4; ++i) {
        unsigned ua = __float_as_uint(a[i]);
        unsigned rh = (ua + 0x7FFFu + ((ua >> 16) & 1u)) & 0xFFFF0000u;
        float lo = a[i] - __uint_as_float(rh);
        unsigned ul = __float_as_uint(lo);
        unsigned rl = ul + 0x7FFFu + ((ul >> 16) & 1u);
        hp[i] = (ushort)(rh >> 16);
        lp[i] = (ushort)(rl >> 16);
    }
    *(ushort4*)(xhi + e) = h;
    *(ushort4*)(xlo + e) = l;
}

// K0b: split W_enc into bf16 hi/lo
__global__ __launch_bounds__(256) void k_split_w(const float* __restrict__ w,
                                                 ushort* __restrict__ whi,
                                                 ushort* __restrict__ wlo) {
    int e = (blockIdx.x * 256 + threadIdx.x) * 4;
    float4 v = *(const float4*)(w + e);
    float a[4] = {v.x, v.y, v.z, v.w};
    ushort4 h, l;
    ushort* hp = (ushort*)&h; ushort* lp = (ushort*)&l;
#pragma unroll
    for (int i = 0; i < 4; ++i) {
        unsigned ua = __float_as_uint(a[i]);
        unsigned rh = (ua + 0x7FFFu + ((ua >> 16) & 1u)) & 0xFFFF0000u;
        float lo = a[i] - __uint_as_float(rh);
        unsigned ul = __float_as_uint(lo);
        unsigned rl = ul + 0x7FFFu + ((ul >> 16) & 1u);
        hp[i] = (ushort)(rh >> 16);
        lp[i] = (ushort)(rl >> 16);
    }
    *(ushort4*)(whi + e) = h;
    *(ushort4*)(wlo + e) = l;
}

// K0c: W_dec [128][4096] -> WdT2 [4096][64] of float2 {w[d], w[d+64]}
__global__ __launch_bounds__(256) void k_transpose(const float* __restrict__ Wdec,
                                                   float2* __restrict__ WdT2) {
    int tid = blockIdx.x * 256 + threadIdx.x;   // 0 .. 4096*64-1
    int l = tid & 63;
    int j = tid >> 6;
    float2 o;
    o.x = Wdec[(size_t)l * MLAT + j];
    o.y = Wdec[(size_t)(l + 64) * MLAT + j];
    WdT2[tid] = o;
}

// ---------------------------------------------------------------------------
// K1: z~ = relu((x-b_dec) @ W_enc^T + b_enc) via split-bf16 MFMA.
// UNCHANGED from R3 (validated numerics -- do not perturb z~ values).
__global__ __launch_bounds__(256, 2) void k_encode_mfma(
        const ushort* __restrict__ xhi, const ushort* __restrict__ xlo,
        const ushort* __restrict__ whi, const ushort* __restrict__ wlo,
        const float* __restrict__ benc, float* __restrict__ zout) {
    __shared__ __attribute__((aligned(16))) ushort Ah[128 * 128];
    __shared__ __attribute__((aligned(16))) ushort Al[128 * 128];

    const int t    = threadIdx.x;
    const int lane = t & 63;
    const int w    = t >> 6;
    const int i0   = blockIdx.x << 7;

    {
        int row = t >> 1, half = t & 1;
        const ushort* sh = xhi + (size_t)(i0 + row) * DDIM + half * 64;
        const ushort* sl = xlo + (size_t)(i0 + row) * DDIM + half * 64;
        int base = row * 256 + half * 128;
        int swz  = (row & 7) << 4;
#pragma unroll
        for (int j = 0; j < 8; ++j) {
            int off = (base + j * 16) ^ swz;
            *(bf16x8*)((char*)Ah + off) = *(const bf16x8*)(sh + j * 8);
            *(bf16x8*)((char*)Al + off) = *(const bf16x8*)(sl + j * 8);
        }
    }
    __syncthreads();

    const int lr = lane & 15;
    const int lq = lane >> 4;

    for (int cp = 0; cp < 16; ++cp) {
        const int jb = cp * 256 + (w << 6);
        f32x4 acc[8][4];
#pragma unroll
        for (int rf = 0; rf < 8; ++rf)
#pragma unroll
            for (int cf = 0; cf < 4; ++cf) acc[rf][cf] = (f32x4){0.f, 0.f, 0.f, 0.f};

        for (int ks = 0; ks < 4; ++ks) {
            bf16x8 bh[4], bl[4];
#pragma unroll
            for (int cf = 0; cf < 4; ++cf) {
                size_t boff = (size_t)(jb + cf * 16 + lr) * DDIM + ks * 32 + lq * 8;
                bh[cf] = *(const bf16x8*)(whi + boff);
                bl[cf] = *(const bf16x8*)(wlo + boff);
            }
#pragma unroll
            for (int rf = 0; rf < 8; ++rf) {
                int row = rf * 16 + lr;
                int off = (row * 256 + ks * 64 + lq * 16) ^ ((row & 7) << 4);
                bf16x8 ah = *(const bf16x8*)((const char*)Ah + off);
                bf16x8 al = *(const bf16x8*)((const char*)Al + off);
#pragma unroll
                for (int cf = 0; cf < 4; ++cf) {
                    acc[rf][cf] = __builtin_amdgcn_mfma_f32_16x16x32_bf16(ah, bh[cf], acc[rf][cf], 0, 0, 0);
                    acc[rf][cf] = __builtin_amdgcn_mfma_f32_16x16x32_bf16(ah, bl[cf], acc[rf][cf], 0, 0, 0);
                    acc[rf][cf] = __builtin_amdgcn_mfma_f32_16x16x32_bf16(al, bh[cf], acc[rf][cf], 0, 0, 0);
                }
            }
        }
#pragma unroll
        for (int rf = 0; rf < 8; ++rf)
#pragma unroll
            for (int cf = 0; cf < 4; ++cf) {
                int col = jb + cf * 16 + lr;
                float be = benc[col];
#pragma unroll
                for (int r = 0; r < 4; ++r) {
                    int row = i0 + rf * 16 + lq * 4 + r;
                    zout[(size_t)row * MLAT + col] = fmaxf(acc[rf][cf][r] + be, 0.f);
                }
            }
    }
}

// ---------------------------------------------------------------------------
// K2 v4: ballot bisection (max-seeded, early exit) for threshold T, then
// R3's provably-exact band classification: values within +-DELTA of tau are
// recomputed with the np-order f32 chain (exact selection by TRUE z).
__device__ __forceinline__ int wredSum(int v) {
#pragma unroll
    for (int d = 32; d >= 1; d >>= 1) v += __shfl_xor(v, d, 64);
    return v;
}

__global__ __launch_bounds__(256) void k_topk_decode(
        float* __restrict__ zbuf, float* __restrict__ xhat,
        const float2* __restrict__ WdT2, const float* __restrict__ bdec,
        const float* __restrict__ x, const float* __restrict__ Wenc,
        const float* __restrict__ benc) {
    __shared__ float sval[4][KSEL];
    __shared__ int   sidx[4][KSEL];
    __shared__ float bval[4][128];
    __shared__ int   bidx[4][128];
    __shared__ unsigned char bselm[4][128];

    const int lane = threadIdx.x & 63;
    const int wid  = threadIdx.x >> 6;
    const size_t row = (size_t)blockIdx.x * 4 + wid;
    float* zr = zbuf + row * MLAT;
    const uint4* zu = (const uint4*)zr;

    // element index: q*256 + lane*4 + c
    uint4 u[16];
#pragma unroll
    for (int q = 0; q < 16; ++q) u[q] = zu[(q << 6) + lane];

    // ---- row max (values >= 0 so uint order == float order)
    unsigned mx = 0u;
#pragma unroll
    for (int q = 0; q < 16; ++q) {
        mx = max(mx, max(max(u[q].x, u[q].y), max(u[q].z, u[q].w)));
    }
#pragma unroll
    for (int d = 32; d >= 1; d >>= 1) mx = max(mx, (unsigned)__shfl_xor((int)mx, d, 64));

    // ---- ballot-based count(v >= T): 1 v_cmp/elem + SALU popcount
#define CNT_GE(T, OUTC)                                              \
    {                                                                \
        int _c = 0;                                                  \
        _Pragma("unroll")                                            \
        for (int q = 0; q < 16; ++q) {                               \
            _c += __popcll(__ballot(u[q].x >= (T)));                 \
            _c += __popcll(__ballot(u[q].y >= (T)));                 \
            _c += __popcll(__ballot(u[q].z >= (T)));                 \
            _c += __popcll(__ballot(u[q].w >= (T)));                 \
        }                                                            \
        OUTC = _c;                                                   \
    }

    // ---- bisection for T: count(>=T) == 64, or tie (T = 64th value's bits)
    unsigned T;
    {
        unsigned hi = mx + 1u;
        unsigned lo = (mx > 0x01800000u) ? (mx - 0x01800000u) : 0u;
        int c;
        CNT_GE(lo, c);
        if (c < KSEL) { lo = 0u; c = MLAT; }   // count(>=0) = 4096 > 64
        if (c == KSEL) {
            T = lo;
        } else {
            // invariant: count(>=lo) > 64, count(>=hi) < 64
            for (;;) {
                if (hi - lo <= 1u) { T = lo; break; }
                unsigned mid = lo + ((hi - lo) >> 1);
                int cm;
                CNT_GE(mid, cm);
                if (cm == KSEL) { T = mid; break; }
                if (cm > KSEL) lo = mid; else hi = mid;
            }
        }
    }

    // ---- R3 band classification around tau (float margins; uint cmp ok, v>=0)
    const float tau   = __uint_as_float(T);
    const float DELTA = 2.5e-4f;   // >> 2*eps(z~) ~ 4e-5
    const float PAD   = 5.0e-5f;   // guard on the IN edge
    const unsigned DH = __float_as_uint(tau + DELTA + PAD);
    const unsigned DL = __float_as_uint(fmaxf(tau - DELTA, 0.f));

    unsigned long long inm = 0ull, bandm = 0ull;
#pragma unroll
    for (int q = 0; q < 16; ++q) {
        unsigned vv[4] = {u[q].x, u[q].y, u[q].z, u[q].w};
#pragma unroll
        for (int c = 0; c < 4; ++c) {
            unsigned long long bit = 1ull << (4 * q + c);
            if (vv[c] > DH) inm |= bit;
            else if (vv[c] >= DL) bandm |= bit;
        }
    }
    int packed = wredSum((__popcll(inm) << 16) | __popcll(bandm));
    int A = packed >> 16, BCt = packed & 0xFFFF;
    int need = KSEL - A;

    unsigned long long sel;
    if (need <= 0) {
        sel = inm;
    } else if (BCt == need) {
        sel = inm | bandm;
    } else {
        // ---- exact fixup: recompute band members with np-order f32 chain
        int BC2 = min(BCt, 128);
        int bc = __popcll(bandm);
        int pre = bc;
#pragma unroll
        for (int d = 1; d < 64; d <<= 1) {
            int y = __shfl_up(pre, d, 64);
            if (lane >= d) pre += y;
        }
        int sbase = pre - bc;
        {
            unsigned long long mm = bandm; int o = 0;
            while (mm) {
                int bp = __ffsll((long long)mm) - 1; mm &= mm - 1;
                int slot = sbase + o; ++o;
                if (slot < 128) bidx[wid][slot] = ((bp >> 2) << 8) + (lane << 2) + (bp & 3);
            }
        }
        for (int s = lane; s < BC2; s += 64) {
            int j = bidx[wid][s];
            const float* wr = Wenc + (size_t)j * DDIM;
            const float* xr = x + row * DDIM;
            float a = 0.f;
            for (int k = 0; k < DDIM; ++k) a = fmaf(xr[k] - bdec[k], wr[k], a);
            bval[wid][s] = fmaxf(a + benc[j], 0.f);
        }
        if (lane == 0) {
            for (int s = 0; s < BC2; ++s) bselm[wid][s] = 0;
            int take = min(need, BC2);
            for (int it = 0; it < take; ++it) {
                float bv = -1.f; int bi = 0x7FFFFFFF, bs = 0;
                for (int s = 0; s < BC2; ++s) {
                    if (bselm[wid][s]) continue;
                    float v = bval[wid][s]; int j = bidx[wid][s];
                    if (v > bv || (v == bv && j < bi)) { bv = v; bi = j; bs = s; }
                }
                bselm[wid][bs] = 1;
            }
        }
        sel = inm;
        {
            unsigned long long mm = bandm; int o = 0;
            while (mm) {
                int bp = __ffsll((long long)mm) - 1; mm &= mm - 1;
                int slot = sbase + o; ++o;
                if (slot < 128 && bselm[wid][slot]) sel |= 1ull << bp;
            }
        }
    }

    // ---- compaction position: exclusive prefix over lanes
    int scnt = __popcll(sel);
    int pre = scnt;
#pragma unroll
    for (int d = 1; d < 64; d <<= 1) {
        int y = __shfl_up(pre, d, 64);
        if (lane >= d) pre += y;
    }
    int pos = pre - scnt;
    int total = __shfl(pre, 63, 64);

    // ---- finalize z in place + compact (v, idx) to LDS
    uint4* zw = (uint4*)zr;
#pragma unroll
    for (int q = 0; q < 16; ++q) {
        uint4 o;
        bool s0 = (sel >> (4 * q + 0)) & 1ull;
        bool s1 = (sel >> (4 * q + 1)) & 1ull;
        bool s2 = (sel >> (4 * q + 2)) & 1ull;
        bool s3 = (sel >> (4 * q + 3)) & 1ull;
        o.x = s0 ? u[q].x : 0u;
        o.y = s1 ? u[q].y : 0u;
        o.z = s2 ? u[q].z : 0u;
        o.w = s3 ? u[q].w : 0u;
        int base = (q << 8) + (lane << 2);
        if (s0) { sval[wid][pos] = __uint_as_float(u[q].x); sidx[wid][pos] = base + 0; ++pos; }
        if (s1) { sval[wid][pos] = __uint_as_float(u[q].y); sidx[wid][pos] = base + 1; ++pos; }
        if (s2) { sval[wid][pos] = __uint_as_float(u[q].z); sidx[wid][pos] = base + 2; ++pos; }
        if (s3) { sval[wid][pos] = __uint_as_float(u[q].w); sidx[wid][pos] = base + 3; ++pos; }
        zw[(q << 6) + lane] = o;
    }
    __syncthreads();

    // ---- decode: lane owns d = lane and d = lane+64 via interleaved float2
    float a0 = bdec[lane], a1 = bdec[64 + lane];
    int tt = min(total, KSEL);
#pragma unroll 4
    for (int s = 0; s < tt; ++s) {
        float v = sval[wid][s];
        int   j = sidx[wid][s];
        float2 wv = WdT2[(size_t)j * 64 + lane];
        a0 = fmaf(v, wv.x, a0);
        a1 = fmaf(v, wv.y, a1);
    }
    xhat[row * DDIM + lane]      = a0;
    xhat[row * DDIM + 64 + lane] = a1;
}

// ---------------------------------------------------------------------------
extern "C" void kernel_launch(void* const* d_in, const int* in_sizes, int n_in,
                              void* d_out, int out_size, void* d_ws, size_t ws_size,
                              hipStream_t stream) {
    const float* x    = (const float*)d_in[0];
    const float* Wenc = (const float*)d_in[1];
    const float* benc = (const float*)d_in[2];
    const float* Wdec = (const float*)d_in[3];
    const float* bdec = (const float*)d_in[4];

    const int N = in_sizes[0] / DDIM;               // 65536
    float* xhat = (float*)d_out;                    // [N][128] f32 (final)
    float* zbuf = (float*)d_out + (size_t)N * DDIM; // [N][4096]

    // x splits live in the xhat region until decode (exact fit: N*128*4 bytes)
    ushort* xhi = (ushort*)d_out;
    ushort* xlo = xhi + (size_t)N * DDIM;

    // workspace: whi | wlo | WdT2  (1 MB + 1 MB + 2 MB)
    ushort* whi = (ushort*)d_ws;
    ushort* wlo = whi + (size_t)MLAT * DDIM;
    float2* WdT2 = (float2*)((char*)d_ws + 2u * 1024u * 1024u);

    k_split_x<<<dim3((N * DDIM) / 1024), dim3(256), 0, stream>>>(x, bdec, xhi, xlo);
    k_split_w<<<dim3((MLAT * DDIM) / 1024), dim3(256), 0, stream>>>(Wenc, whi, wlo);
    k_transpose<<<dim3((MLAT * 64) / 256), dim3(256), 0, stream>>>(Wdec, WdT2);
    k_encode_mfma<<<dim3(N / 128), dim3(256), 0, stream>>>(xhi, xlo, whi, wlo, benc, zbuf);
    k_topk_decode<<<dim3(N / 4), dim3(256), 0, stream>>>(zbuf, xhat, WdT2, bdec, x, Wenc, benc);
}

// Round 6
// 888.743 us; speedup vs baseline: 2.1563x; 1.2582x over previous
//
#include <hip/hip_runtime.h>
#include <cstdint>

#define DDIM 128
#define MLAT 4096
#define KSEL 64

typedef __bf16 bf16x8 __attribute__((ext_vector_type(8)));
typedef float  f32x4  __attribute__((ext_vector_type(4)));

// ---------------------------------------------------------------------------
// K0a: split (x - b_dec) into bf16 hi/lo pair arrays (RN-even), 4 elems/thread
__global__ __launch_bounds__(256) void k_split_x(const float* __restrict__ x,
                                                 const float* __restrict__ bdec,
                                                 ushort* __restrict__ xhi,
                                                 ushort* __restrict__ xlo) {
    int e = (blockIdx.x * 256 + threadIdx.x) * 4;
    float4 v = *(const float4*)(x + e);
    float4 bd = *(const float4*)(bdec + (e & 127));
    float a[4] = {v.x - bd.x, v.y - bd.y, v.z - bd.z, v.w - bd.w};
    ushort4 h, l;
    ushort* hp = (ushort*)&h; ushort* lp = (ushort*)&l;
#pragma unroll
    for (int i = 0; i < 4; ++i) {
        unsigned ua = __float_as_uint(a[i]);
        unsigned rh = (ua + 0x7FFFu + ((ua >> 16) & 1u)) & 0xFFFF0000u;
        float lo = a[i] - __uint_as_float(rh);
        unsigned ul = __float_as_uint(lo);
        unsigned rl = ul + 0x7FFFu + ((ul >> 16) & 1u);
        hp[i] = (ushort)(rh >> 16);
        lp[i] = (ushort)(rl >> 16);
    }
    *(ushort4*)(xhi + e) = h;
    *(ushort4*)(xlo + e) = l;
}

// K0b: split W_enc into bf16 hi/lo
__global__ __launch_bounds__(256) void k_split_w(const float* __restrict__ w,
                                                 ushort* __restrict__ whi,
                                                 ushort* __restrict__ wlo) {
    int e = (blockIdx.x * 256 + threadIdx.x) * 4;
    float4 v = *(const float4*)(w + e);
    float a[4] = {v.x, v.y, v.z, v.w};
    ushort4 h, l;
    ushort* hp = (ushort*)&h; ushort* lp = (ushort*)&l;
#pragma unroll
    for (int i = 0; i < 4; ++i) {
        unsigned ua = __float_as_uint(a[i]);
        unsigned rh = (ua + 0x7FFFu + ((ua >> 16) & 1u)) & 0xFFFF0000u;
        float lo = a[i] - __uint_as_float(rh);
        unsigned ul = __float_as_uint(lo);
        unsigned rl = ul + 0x7FFFu + ((ul >> 16) & 1u);
        hp[i] = (ushort)(rh >> 16);
        lp[i] = (ushort)(rl >> 16);
    }
    *(ushort4*)(whi + e) = h;
    *(ushort4*)(wlo + e) = l;
}

// K0c: transpose W_dec [128][4096] -> WdT [4096][128]
__global__ __launch_bounds__(256) void k_transpose(const float* __restrict__ Wdec,
                                                   float* __restrict__ WdT) {
    int tid = blockIdx.x * 256 + threadIdx.x;   // j*128 + d
    int d = tid & (DDIM - 1);
    int j = tid >> 7;
    WdT[tid] = Wdec[(size_t)d * MLAT + j];
}

// ---------------------------------------------------------------------------
// K1: z~ = relu((x-b_dec) @ W_enc^T + b_enc) via split-bf16 MFMA.
// UNCHANGED (validated numerics -- do not perturb z~ values).
__global__ __launch_bounds__(256, 2) void k_encode_mfma(
        const ushort* __restrict__ xhi, const ushort* __restrict__ xlo,
        const ushort* __restrict__ whi, const ushort* __restrict__ wlo,
        const float* __restrict__ benc, float* __restrict__ zout) {
    __shared__ __attribute__((aligned(16))) ushort Ah[128 * 128];
    __shared__ __attribute__((aligned(16))) ushort Al[128 * 128];

    const int t    = threadIdx.x;
    const int lane = t & 63;
    const int w    = t >> 6;
    const int i0   = blockIdx.x << 7;

    {
        int row = t >> 1, half = t & 1;
        const ushort* sh = xhi + (size_t)(i0 + row) * DDIM + half * 64;
        const ushort* sl = xlo + (size_t)(i0 + row) * DDIM + half * 64;
        int base = row * 256 + half * 128;
        int swz  = (row & 7) << 4;
#pragma unroll
        for (int j = 0; j < 8; ++j) {
            int off = (base + j * 16) ^ swz;
            *(bf16x8*)((char*)Ah + off) = *(const bf16x8*)(sh + j * 8);
            *(bf16x8*)((char*)Al + off) = *(const bf16x8*)(sl + j * 8);
        }
    }
    __syncthreads();

    const int lr = lane & 15;
    const int lq = lane >> 4;

    for (int cp = 0; cp < 16; ++cp) {
        const int jb = cp * 256 + (w << 6);
        f32x4 acc[8][4];
#pragma unroll
        for (int rf = 0; rf < 8; ++rf)
#pragma unroll
            for (int cf = 0; cf < 4; ++cf) acc[rf][cf] = (f32x4){0.f, 0.f, 0.f, 0.f};

        for (int ks = 0; ks < 4; ++ks) {
            bf16x8 bh[4], bl[4];
#pragma unroll
            for (int cf = 0; cf < 4; ++cf) {
                size_t boff = (size_t)(jb + cf * 16 + lr) * DDIM + ks * 32 + lq * 8;
                bh[cf] = *(const bf16x8*)(whi + boff);
                bl[cf] = *(const bf16x8*)(wlo + boff);
            }
#pragma unroll
            for (int rf = 0; rf < 8; ++rf) {
                int row = rf * 16 + lr;
                int off = (row * 256 + ks * 64 + lq * 16) ^ ((row & 7) << 4);
                bf16x8 ah = *(const bf16x8*)((const char*)Ah + off);
                bf16x8 al = *(const bf16x8*)((const char*)Al + off);
#pragma unroll
                for (int cf = 0; cf < 4; ++cf) {
                    acc[rf][cf] = __builtin_amdgcn_mfma_f32_16x16x32_bf16(ah, bh[cf], acc[rf][cf], 0, 0, 0);
                    acc[rf][cf] = __builtin_amdgcn_mfma_f32_16x16x32_bf16(ah, bl[cf], acc[rf][cf], 0, 0, 0);
                    acc[rf][cf] = __builtin_amdgcn_mfma_f32_16x16x32_bf16(al, bh[cf], acc[rf][cf], 0, 0, 0);
                }
            }
        }
#pragma unroll
        for (int rf = 0; rf < 8; ++rf)
#pragma unroll
            for (int cf = 0; cf < 4; ++cf) {
                int col = jb + cf * 16 + lr;
                float be = benc[col];
#pragma unroll
                for (int r = 0; r < 4; ++r) {
                    int row = i0 + rf * 16 + lq * 4 + r;
                    zout[(size_t)row * MLAT + col] = fmaxf(acc[rf][cf][r] + be, 0.f);
                }
            }
    }
}

// ---------------------------------------------------------------------------
// K2 v5: 2 waves per row (u[8] each, VGPR<=64 -> 8 waves/SIMD). Ballot
// bisection with LDS-combined counts; R5's exact band classification and
// np-order fixup, decision-identical. Decode: 1 thread per output dim.
__global__ __launch_bounds__(128, 8) void k_topk_decode(
        float* __restrict__ zbuf, float* __restrict__ xhat,
        const float* __restrict__ WdT, const float* __restrict__ bdec,
        const float* __restrict__ x, const float* __restrict__ Wenc,
        const float* __restrict__ benc) {
    __shared__ float sval[KSEL];
    __shared__ int   sidx[KSEL];
    __shared__ float bval[128];
    __shared__ int   bidx[128];
    __shared__ unsigned char bselm[128];
    __shared__ unsigned scom[4];
    __shared__ int stot[2];

    const int tid  = threadIdx.x;     // 0..127
    const int lane = tid & 63;
    const int w    = tid >> 6;        // wave 0/1: owns elements w*2048 ..
    const size_t row = blockIdx.x;
    float* zr = zbuf + row * MLAT;
    const uint4* zu = (const uint4*)zr + (w << 9);

    // element (half-local): q*256 + lane*4 + c ; global = w*2048 + that
    uint4 u[8];
#pragma unroll
    for (int q = 0; q < 8; ++q) u[q] = zu[(q << 6) + lane];

    // ---- row max (v >= 0 so uint order == float order)
    unsigned mx = 0u;
#pragma unroll
    for (int q = 0; q < 8; ++q)
        mx = max(mx, max(max(u[q].x, u[q].y), max(u[q].z, u[q].w)));
#pragma unroll
    for (int d = 32; d >= 1; d >>= 1) mx = max(mx, (unsigned)__shfl_xor((int)mx, d, 64));
    if (lane == 0) scom[w] = mx;
    __syncthreads();
    mx = max(scom[0], scom[1]);
    __syncthreads();

    // ---- distributed count(v >= T): ballots per wave + LDS combine
#define CNT_GE(T, OUTC)                                              \
    {                                                                \
        int _c = 0;                                                  \
        _Pragma("unroll")                                            \
        for (int q = 0; q < 8; ++q) {                                \
            _c += __popcll(__ballot(u[q].x >= (T)));                 \
            _c += __popcll(__ballot(u[q].y >= (T)));                 \
            _c += __popcll(__ballot(u[q].z >= (T)));                 \
            _c += __popcll(__ballot(u[q].w >= (T)));                 \
        }                                                            \
        if (lane == 0) scom[2 + w] = (unsigned)_c;                   \
        __syncthreads();                                             \
        OUTC = (int)(scom[2] + scom[3]);                             \
        __syncthreads();                                             \
    }

    // ---- bisection for T (same decisions as R5: seed window, early exit)
    unsigned T;
    {
        unsigned hi = mx + 1u;
        unsigned lo = (mx > 0x01800000u) ? (mx - 0x01800000u) : 0u;
        int c;
        CNT_GE(lo, c);
        if (c < KSEL) { lo = 0u; c = MLAT; }
        if (c == KSEL) {
            T = lo;
        } else {
            for (;;) {
                if (hi - lo <= 1u) { T = lo; break; }
                unsigned mid = lo + ((hi - lo) >> 1);
                int cm;
                CNT_GE(mid, cm);
                if (cm == KSEL) { T = mid; break; }
                if (cm > KSEL) lo = mid; else hi = mid;
            }
        }
    }

    // ---- band classification (identical constants to R5)
    const float tau   = __uint_as_float(T);
    const float DELTA = 2.5e-4f;
    const float PAD   = 5.0e-5f;
    const unsigned DH = __float_as_uint(tau + DELTA + PAD);
    const unsigned DL = __float_as_uint(fmaxf(tau - DELTA, 0.f));

    unsigned inm = 0u, bandm = 0u;   // per-lane 32-bit masks, bit = q*4+c
#pragma unroll
    for (int q = 0; q < 8; ++q) {
        unsigned vv[4] = {u[q].x, u[q].y, u[q].z, u[q].w};
#pragma unroll
        for (int c = 0; c < 4; ++c) {
            unsigned bit = 1u << (4 * q + c);
            if (vv[c] > DH) inm |= bit;
            else if (vv[c] >= DL) bandm |= bit;
        }
    }
    {
        int packed = (__popc(inm) << 16) | __popc(bandm);
#pragma unroll
        for (int d = 32; d >= 1; d >>= 1) packed += __shfl_xor(packed, d, 64);
        if (lane == 0) scom[2 + w] = (unsigned)packed;
        __syncthreads();
    }
    int A   = (int)((scom[2] >> 16) + (scom[3] >> 16));
    int BCt = (int)((scom[2] & 0xFFFFu) + (scom[3] & 0xFFFFu));
    __syncthreads();
    int need = KSEL - A;

    unsigned sel;
    if (need <= 0) {
        sel = inm;
    } else if (BCt == need) {
        sel = inm | bandm;
    } else {
        // ---- exact fixup: recompute band members with np-order f32 chain
        int BC2 = min(BCt, 128);
        int bc = __popc(bandm);
        int pre = bc;
#pragma unroll
        for (int d = 1; d < 64; d <<= 1) {
            int y = __shfl_up(pre, d, 64);
            if (lane >= d) pre += y;
        }
        int wtot = __shfl(pre, 63, 64);
        if (lane == 0) stot[w] = wtot;
        __syncthreads();
        int sbase = (pre - bc) + (w ? stot[0] : 0);
        {
            unsigned mm = bandm; int o = 0;
            while (mm) {
                int bp = __ffs(mm) - 1; mm &= mm - 1;
                int slot = sbase + o; ++o;
                if (slot < 128)
                    bidx[slot] = (w << 11) + ((bp >> 2) << 8) + (lane << 2) + (bp & 3);
            }
        }
        __syncthreads();
        for (int s = tid; s < BC2; s += 128) {
            int j = bidx[s];
            const float* wr = Wenc + (size_t)j * DDIM;
            const float* xr = x + row * DDIM;
            float a = 0.f;
            for (int k = 0; k < DDIM; ++k) a = fmaf(xr[k] - bdec[k], wr[k], a);
            bval[s] = fmaxf(a + benc[j], 0.f);
        }
        __syncthreads();
        if (tid == 0) {
            for (int s = 0; s < BC2; ++s) bselm[s] = 0;
            int take = min(need, BC2);
            for (int it = 0; it < take; ++it) {
                float bv = -1.f; int bi = 0x7FFFFFFF, bs = 0;
                for (int s = 0; s < BC2; ++s) {
                    if (bselm[s]) continue;
                    float v = bval[s]; int j = bidx[s];
                    if (v > bv || (v == bv && j < bi)) { bv = v; bi = j; bs = s; }
                }
                bselm[bs] = 1;
            }
        }
        __syncthreads();
        sel = inm;
        {
            unsigned mm = bandm; int o = 0;
            while (mm) {
                int bp = __ffs(mm) - 1; mm &= mm - 1;
                int slot = sbase + o; ++o;
                if (slot < 128 && bselm[slot]) sel |= 1u << bp;
            }
        }
        __syncthreads();
    }

    // ---- compaction position across both waves
    int scnt = __popc(sel);
    int pre = scnt;
#pragma unroll
    for (int d = 1; d < 64; d <<= 1) {
        int y = __shfl_up(pre, d, 64);
        if (lane >= d) pre += y;
    }
    int wtot2 = __shfl(pre, 63, 64);
    if (lane == 0) stot[w] = wtot2;
    __syncthreads();
    int pos = pre - scnt + (w ? stot[0] : 0);
    int total = stot[0] + stot[1];

    // ---- finalize z (own half) + compact (v, idx) to LDS
    uint4* zw = (uint4*)zr + (w << 9);
#pragma unroll
    for (int q = 0; q < 8; ++q) {
        uint4 o;
        bool s0 = (sel >> (4 * q + 0)) & 1u;
        bool s1 = (sel >> (4 * q + 1)) & 1u;
        bool s2 = (sel >> (4 * q + 2)) & 1u;
        bool s3 = (sel >> (4 * q + 3)) & 1u;
        o.x = s0 ? u[q].x : 0u;
        o.y = s1 ? u[q].y : 0u;
        o.z = s2 ? u[q].z : 0u;
        o.w = s3 ? u[q].w : 0u;
        int base = (w << 11) + (q << 8) + (lane << 2);
        if (s0 && pos < KSEL) { sval[pos] = __uint_as_float(u[q].x); sidx[pos] = base + 0; ++pos; }
        if (s1 && pos < KSEL) { sval[pos] = __uint_as_float(u[q].y); sidx[pos] = base + 1; ++pos; }
        if (s2 && pos < KSEL) { sval[pos] = __uint_as_float(u[q].z); sidx[pos] = base + 2; ++pos; }
        if (s3 && pos < KSEL) { sval[pos] = __uint_as_float(u[q].w); sidx[pos] = base + 3; ++pos; }
        zw[(q << 6) + lane] = o;
    }
    __syncthreads();

    // ---- decode: thread tid owns output dim d = tid; WdT row reads are
    // 512 B contiguous per step; (v, j) broadcast from LDS
    float a = bdec[tid];
    int tt = min(total, KSEL);
#pragma unroll 4
    for (int s = 0; s < tt; ++s) {
        float v = sval[s];
        int   j = sidx[s];
        a = fmaf(v, WdT[(size_t)j * DDIM + tid], a);
    }
    xhat[row * DDIM + tid] = a;
}

// ---------------------------------------------------------------------------
extern "C" void kernel_launch(void* const* d_in, const int* in_sizes, int n_in,
                              void* d_out, int out_size, void* d_ws, size_t ws_size,
                              hipStream_t stream) {
    const float* x    = (const float*)d_in[0];
    const float* Wenc = (const float*)d_in[1];
    const float* benc = (const float*)d_in[2];
    const float* Wdec = (const float*)d_in[3];
    const float* bdec = (const float*)d_in[4];

    const int N = in_sizes[0] / DDIM;               // 65536
    float* xhat = (float*)d_out;                    // [N][128] f32 (final)
    float* zbuf = (float*)d_out + (size_t)N * DDIM; // [N][4096]

    // x splits live in the xhat region until decode (exact fit)
    ushort* xhi = (ushort*)d_out;
    ushort* xlo = xhi + (size_t)N * DDIM;

    // workspace: whi | wlo | WdT  (1 MB + 1 MB + 2 MB)
    ushort* whi = (ushort*)d_ws;
    ushort* wlo = whi + (size_t)MLAT * DDIM;
    float*  WdT = (float*)((char*)d_ws + 2u * 1024u * 1024u);

    k_split_x<<<dim3((N * DDIM) / 1024), dim3(256), 0, stream>>>(x, bdec, xhi, xlo);
    k_split_w<<<dim3((MLAT * DDIM) / 1024), dim3(256), 0, stream>>>(Wenc, whi, wlo);
    k_transpose<<<dim3((MLAT * DDIM) / 256), dim3(256), 0, stream>>>(Wdec, WdT);
    k_encode_mfma<<<dim3(N / 128), dim3(256), 0, stream>>>(xhi, xlo, whi, wlo, benc, zbuf);
    k_topk_decode<<<dim3(N), dim3(128), 0, stream>>>(zbuf, xhat, WdT, bdec, x, Wenc, benc);
}